// Round 2
// baseline (68388.495 us; speedup 1.0000x reference)
//
#include <hip/hip_runtime.h>
#include <cmath>

// ---------------------------------------------------------------------------
// MaSST: memory-augmented GRU scan. T=128, B=32, F=500, H=512, M=64, HEAD=64.
// Strategy: hoist all x-dependent GEMMs out of the scan; cache per-slot
// h@Whh2 (G2) and slot MLP outputs; persistent kernel with global barriers.
// Everything fp32 (argmax flip sensitivity: score error must be <~1e-5).
// ---------------------------------------------------------------------------

#define NWG 256
#define NEGV -9999999.0f

constexpr size_t OXP   = 0;                         // xp [4096,512]
constexpr size_t OGIXM = OXP   + 4096ull*512;       // xp@w_ih[:512]+b_ih [4096,1536]
constexpr size_t OPI   = OGIXM + 4096ull*1536;      // xp@w_ih[512:]      [4096,1536]
constexpr size_t OGIXA = OPI   + 4096ull*1536;      // xp@aux_wih[:512]+aux_bih [4096,390]
constexpr size_t OIHID = OGIXA + 4096ull*390;       // relu(xp@ifc_w1+b1) [4096,32]
constexpr size_t OIMLPX= OIHID + 4096ull*32;        // sigmoid(ihid@ifc_w2+b2) [4096,64]
constexpr size_t OHT   = OIMLPX+ 4096ull*64;        // h transposed [512][32]
constexpr size_t OAUXT = OHT   + 512ull*32;         // aux transposed [130][32]
constexpr size_t ORH   = OAUXT + 130ull*32;         // read_head [32][130]
constexpr size_t OG1   = ORH   + 130ull*32;         // h@Whh1+b_hh [32][1536]
constexpr size_t OG2   = OG1   + 32ull*1536;        // h@Whh2      [32][1536]
constexpr size_t OHG2  = OG2   + 32ull*1536;        // cache: hmem_slot@Whh2 [32][64][1536]
constexpr size_t OIC   = OHG2  + 32ull*64*1536;     // i mlp cache [32][64][64]
constexpr size_t OHC   = OIC   + 32ull*64*64;       // h mlp cache [32][64][64]
constexpr size_t OILU  = OHC   + 32ull*64*64;       // [32][64]
constexpr size_t OHLU  = OILU  + 2048;
constexpr size_t OISL  = OHLU  + 2048;              // int: slot -> time (or -1)
constexpr size_t OHID  = OISL  + 2048;              // hidden dbuf [2][32][32]
constexpr size_t OPEND = OHID  + 2048;              // int pend [32][8]
constexpr size_t OBAR  = OPEND + 256;               // int barrier counter
constexpr size_t OYS   = OBAR  + 64;                // ys [4096,512]
constexpr size_t OTOT  = OYS   + 4096ull*512;

__device__ float g_mem[OTOT];

__device__ __forceinline__ float sigm(float x){ return 1.0f/(1.0f+expf(-x)); }

// ---------------------------------------------------------------------------
__global__ void k_init() {
  size_t i = (size_t)blockIdx.x*blockDim.x + threadIdx.x;
  size_t st = (size_t)gridDim.x*blockDim.x;
  for (size_t k=i; k<32ull*64*1536; k+=st) g_mem[OHG2+k]=0.f;
  for (size_t k=i; k<32ull*64*64; k+=st){ g_mem[OIC+k]=0.5f; g_mem[OHC+k]=0.5f; } // MLP(0)=sigmoid(0)=0.5
  for (size_t k=i; k<2048; k+=st){ g_mem[OILU+k]=NEGV; g_mem[OHLU+k]=NEGV; ((int*)(g_mem+OISL))[k]=-1; }
  for (size_t k=i; k<512ull*32; k+=st) g_mem[OHT+k]=0.f;
  for (size_t k=i; k<130ull*32; k+=st) g_mem[OAUXT+k]=0.f;
  for (size_t k=i; k<320; k+=st) ((int*)(g_mem+OPEND))[k]=0;   // pend(256) + bar(64)
}

// ---------------------------------------------------------------------------
// Generic fp32 tiled GEMM: C[M=4096, N] = act(A[4096,K] @ B[K,N] + bias)
// act: 0 none, 1 relu, 2 sigmoid.
__global__ __launch_bounds__(256) void k_gemm(
    const float* __restrict__ A, int lda,
    const float* __restrict__ B, int ldb,
    const float* __restrict__ bias,
    float* __restrict__ C, int ldc,
    int N, int K, int act)
{
  __shared__ float As[16][64];
  __shared__ float Bs[16][68];
  const int tid = threadIdx.x;
  const int row0 = blockIdx.x*64;
  const int col0 = blockIdx.y*64;
  const int tm = tid>>4, tn = tid&15;
  const int am = tid>>2, akq = tid&3;
  const int bk = tid>>4, bnq = tid&15;
  float acc[4][4] = {};
  for (int k0=0; k0<K; k0+=16) {
    { // stage A (64 rows x 16 k), store transposed As[k][m]
      int ak = k0 + akq*4;
      const float* Ap = A + (size_t)(row0+am)*lda + ak;
      float4 av;
      if (ak+3 < K) av = *(const float4*)Ap;
      else {
        av.x=(ak+0<K)?Ap[0]:0.f; av.y=(ak+1<K)?Ap[1]:0.f;
        av.z=(ak+2<K)?Ap[2]:0.f; av.w=(ak+3<K)?Ap[3]:0.f;
      }
      As[akq*4+0][am]=av.x; As[akq*4+1][am]=av.y; As[akq*4+2][am]=av.z; As[akq*4+3][am]=av.w;
    }
    { // stage B (16 k x 64 n)
      int kk = k0 + bk;
      int cb = col0 + bnq*4;
      float4 bv = {0.f,0.f,0.f,0.f};
      if (kk < K) {
        const float* Bp = B + (size_t)kk*ldb + cb;
        if (cb+3 < N && ((((size_t)kk*ldb + (size_t)cb)&3)==0)) bv = *(const float4*)Bp;
        else {
          bv.x=(cb+0<N)?Bp[0]:0.f; bv.y=(cb+1<N)?Bp[1]:0.f;
          bv.z=(cb+2<N)?Bp[2]:0.f; bv.w=(cb+3<N)?Bp[3]:0.f;
        }
      }
      Bs[bk][bnq*4+0]=bv.x; Bs[bk][bnq*4+1]=bv.y; Bs[bk][bnq*4+2]=bv.z; Bs[bk][bnq*4+3]=bv.w;
    }
    __syncthreads();
    #pragma unroll
    for (int k=0;k<16;++k) {
      float a0=As[k][tm*4+0], a1=As[k][tm*4+1], a2=As[k][tm*4+2], a3=As[k][tm*4+3];
      float b0=Bs[k][tn*4+0], b1=Bs[k][tn*4+1], b2=Bs[k][tn*4+2], b3=Bs[k][tn*4+3];
      acc[0][0]=fmaf(a0,b0,acc[0][0]); acc[0][1]=fmaf(a0,b1,acc[0][1]);
      acc[0][2]=fmaf(a0,b2,acc[0][2]); acc[0][3]=fmaf(a0,b3,acc[0][3]);
      acc[1][0]=fmaf(a1,b0,acc[1][0]); acc[1][1]=fmaf(a1,b1,acc[1][1]);
      acc[1][2]=fmaf(a1,b2,acc[1][2]); acc[1][3]=fmaf(a1,b3,acc[1][3]);
      acc[2][0]=fmaf(a2,b0,acc[2][0]); acc[2][1]=fmaf(a2,b1,acc[2][1]);
      acc[2][2]=fmaf(a2,b2,acc[2][2]); acc[2][3]=fmaf(a2,b3,acc[2][3]);
      acc[3][0]=fmaf(a3,b0,acc[3][0]); acc[3][1]=fmaf(a3,b1,acc[3][1]);
      acc[3][2]=fmaf(a3,b2,acc[3][2]); acc[3][3]=fmaf(a3,b3,acc[3][3]);
    }
    __syncthreads();
  }
  for (int i=0;i<4;++i)
    for (int j2=0;j2<4;++j2) {
      int r = row0+tm*4+i, c = col0+tn*4+j2;
      if (c<N) {
        float v = acc[i][j2] + (bias? bias[c]:0.f);
        if (act==1) v = fmaxf(v,0.f);
        else if (act==2) v = 1.f/(1.f+expf(-v));
        C[(size_t)r*ldc + c] = v;
      }
    }
}

// ---------------------------------------------------------------------------
// Global barrier: monotonic counter, barrier #n passes when cnt >= n*NWG.
__device__ __forceinline__ void gbar(int n, int& alive) {
  __syncthreads();
  if (threadIdx.x==0 && alive) {
    int* bar = (int*)(g_mem+OBAR);
    __threadfence();                 // release: flush my writes to coherence point
    atomicAdd(bar, 1);
    const int target = n*NWG;
    int guard = 0;
    while (__hip_atomic_load(bar, __ATOMIC_ACQUIRE, __HIP_MEMORY_SCOPE_AGENT) < target) {
      __builtin_amdgcn_s_sleep(1);
      if (++guard > (1<<22)) { alive=0; break; }   // bail instead of hanging
    }
    __threadfence();                 // acquire: invalidate stale cached lines
  }
  __syncthreads();
}

// ---------------------------------------------------------------------------
__global__ __launch_bounds__(256,1) void k_scan(
    const float* __restrict__ w_hh, const float* __restrict__ b_hh,
    const float* __restrict__ aux_wih, const float* __restrict__ aux_whh,
    const float* __restrict__ aux_bhh,
    const float* __restrict__ hfc_w1, const float* __restrict__ hfc_b1,
    const float* __restrict__ hfc_w2, const float* __restrict__ hfc_b2,
    const float* __restrict__ gum_i, const float* __restrict__ gum_h,
    const int* __restrict__ length)
{
  const int wg  = blockIdx.x;
  const int tid = threadIdx.x;
  float* const mem = g_mem;
  int*  const islot = (int*)(mem+OISL);
  int*  const pend  = (int*)(mem+OPEND);

  __shared__ float s_red[2][4][64];
  __shared__ float s_sp[5][4][2][32];
  __shared__ float s_ph[32][9];
  __shared__ float s_rhs[132];
  __shared__ float s_sv[128];
  __shared__ int   s_si[128];
  __shared__ int   s_sel[4];
  __shared__ int   s_pd[8];

  int alive = 1;

  #pragma unroll 1
  for (int t=0; t<128; ++t) {
    // ================= H-phase: everything depending only on carry h/aux ====
    if (wg < 192) {
      // G1 = h@Whh1 + b_hh ; G2 = h@Whh2.  3072 virtual cols over 48 groups.
      const int cg = wg>>2, bg = wg&3;
      const int wave = tid>>6, lane = tid&63;
      const int vcol = cg*64 + lane;
      const int isG2 = vcol>=1536;
      const int col  = isG2? vcol-1536 : vcol;
      const float* Wp = w_hh + (size_t)(isG2?512:0)*1536 + col;
      const int bh = wave>>1, kh = wave&1;
      const int b0 = bg*8 + bh*4;
      const float* hTp = mem+OHT;
      float a0=0.f,a1=0.f,a2=0.f,a3=0.f;
      const int kbeg = kh*256;
      #pragma unroll 4
      for (int k=kbeg; k<kbeg+256; ++k) {
        const float w = Wp[(size_t)k*1536];
        const float4 hv = *(const float4*)(hTp + (k<<5) + b0);
        a0 = fmaf(w,hv.x,a0); a1 = fmaf(w,hv.y,a1);
        a2 = fmaf(w,hv.z,a2); a3 = fmaf(w,hv.w,a3);
      }
      if (kh) { s_red[bh][0][lane]=a0; s_red[bh][1][lane]=a1; s_red[bh][2][lane]=a2; s_red[bh][3][lane]=a3; }
      __syncthreads();
      if (!kh) {
        a0+=s_red[bh][0][lane]; a1+=s_red[bh][1][lane]; a2+=s_red[bh][2][lane]; a3+=s_red[bh][3][lane];
        const float bias = isG2 ? 0.f : b_hh[vcol];
        float* Gp = mem + (isG2? OG2 : OG1);
        Gp[(size_t)(b0+0)*1536+col]=a0+bias;
        Gp[(size_t)(b0+1)*1536+col]=a1+bias;
        Gp[(size_t)(b0+2)*1536+col]=a2+bias;
        Gp[(size_t)(b0+3)*1536+col]=a3+bias;
      }
    } else if (wg < 224) {
      // aux GRU read_head. rh-cols [c0,c1) for this WG.
      const int a = wg-192;
      const int c0 = (a*130)>>5, c1 = ((a+1)*130)>>5;
      const int nc = c1-c0;
      const int nt = nc*256;
      const float* hTp = mem+OHT;
      const float* axp = mem+OAUXT;
      for (int task=tid; task<nt; task+=256) {
        const int b=task&31, kh=(task>>5)&1, gate=(task>>6)&3, rcl=task>>8;
        const int c = c0+rcl;
        float acc=0.f;
        if (gate != 3) {                       // h-part dot (r,z merged; n separate)
          const int gc = (gate==2? 260 : gate*130) + c;
          const float* W = aux_wih + (size_t)512*390 + gc;
          const int kb = kh*256;
          #pragma unroll 4
          for (int k=kb;k<kb+256;++k) acc = fmaf(hTp[(k<<5)+b], W[(size_t)k*390], acc);
        }
        if (gate != 2) {                       // aux-part dot
          const int gc = (gate==3? 260 : gate*130) + c;
          const float* W2 = aux_whh + gc;
          const int kb = kh*65;
          for (int k=kb;k<kb+65;++k) acc = fmaf(axp[(k<<5)+b], W2[(size_t)k*390], acc);
        }
        s_sp[rcl][gate][kh][b] = acc;
      }
      __syncthreads();
      for (int task=tid; task<nc*32; task+=256) {
        const int b=task&31, rcl=task>>5;
        const int c=c0+rcl;
        const size_t base=((size_t)t*32+b)*390;
        const float r = sigm(mem[OGIXA+base+c]     + aux_bhh[c]     + s_sp[rcl][0][0][b]+s_sp[rcl][0][1][b]);
        const float z = sigm(mem[OGIXA+base+130+c] + aux_bhh[130+c] + s_sp[rcl][1][0][b]+s_sp[rcl][1][1][b]);
        const float gin = mem[OGIXA+base+260+c] + s_sp[rcl][2][0][b]+s_sp[rcl][2][1][b];
        const float ghn = aux_bhh[260+c]        + s_sp[rcl][3][0][b]+s_sp[rcl][3][1][b];
        const float n = tanhf(gin + r*ghn);
        mem[ORH + (size_t)b*130 + c] = (1.f-z)*n + z*axp[(c<<5)+b];
      }
    } else {
      // mlph WG: deferred cache updates from step t-1, then hidden = relu(h@hfc_w1)
      const int b = wg-224;
      if (tid<8) s_pd[tid] = pend[b*8+tid];
      __syncthreads();
      if (s_pd[0]) {
        const int tp=s_pd[1], isel=s_pd[2], hsel=s_pd[3], wsi=s_pd[4], wsh=s_pd[5];
        if (tid<64) {
          mem[OIC + ((size_t)b*64+wsi)*64 + tid] = mem[OIMLPX + ((size_t)tp*32+b)*64 + tid];
        } else if (tid<128) {
          const int j2=tid-64;
          float s = hfc_b2[j2];
          const float* hid = mem + OHID + (size_t)(tp&1)*1024 + b*32;
          #pragma unroll 8
          for (int q=0;q<32;++q) s = fmaf(hid[q], hfc_w2[(size_t)q*64+j2], s);
          mem[OHC + ((size_t)b*64+wsh)*64 + j2] = sigm(s);
        } else if (tid<192) {
          const int m=tid-128;
          const float v = mem[OILU + b*64 + m];
          mem[OILU + b*64 + m] = (m==isel)? 0.f : (v-1.f);
        } else {
          const int m=tid-192;
          const float v = mem[OHLU + b*64 + m];
          mem[OHLU + b*64 + m] = (m==hsel)? 0.f : (v-1.f);
        }
        if (tid==0) islot[b*64+wsi] = tp;
      }
      __syncthreads();
      { // hidden_new
        const int j = tid&31, kq = tid>>5;
        const float* hTp = mem+OHT;
        float acc=0.f;
        const int kb = kq*64;
        #pragma unroll 4
        for (int k=kb;k<kb+64;++k) acc = fmaf(hTp[(k<<5)+b], hfc_w1[(size_t)k*32+j], acc);
        s_ph[j][kq]=acc;
      }
      __syncthreads();
      if (tid<32) {
        float s = hfc_b1[tid];
        #pragma unroll
        for (int q=0;q<8;++q) s += s_ph[tid][q];
        mem[OHID + (size_t)(t&1)*1024 + b*32 + tid] = fmaxf(s,0.f);
      }
    }
    gbar(2*t+1, alive);

    // ================= S-phase: scores, argmax, gather, gate combine ========
    {
      const int b = wg>>3, j = wg&7;
      if (tid<130) s_rhs[tid] = mem[ORH + (size_t)b*130 + tid];
      __syncthreads();
      if (tid<128) {
        const int head=tid>>6, m=tid&63;
        const float* cache = mem + (head? OHC:OIC) + ((size_t)b*64+m)*64;
        const float* rh = s_rhs + head*65;
        float acc=0.f;
        #pragma unroll 16
        for (int k=0;k<64;++k) acc = fmaf(rh[k], cache[k], acc);
        const float lu = mem[(head? OHLU:OILU) + b*64 + m];
        acc += rh[64]*sigm(lu);
        acc += (head? gum_h:gum_i)[((size_t)t*32+b)*64+m];
        s_sv[tid]=acc; s_si[tid]=m;
      }
      __syncthreads();
      for (int off=32; off>0; off>>=1) {
        if (tid<128 && (tid&63)<off) {
          const float v2=s_sv[tid+off]; const int i2=s_si[tid+off];
          if (v2>s_sv[tid] || (v2==s_sv[tid] && i2<s_si[tid])) { s_sv[tid]=v2; s_si[tid]=i2; }
        }
        __syncthreads();
      }
      if (tid==0) { s_sel[0]=s_si[0]; s_sel[1]=s_si[64]; s_sel[2]=islot[b*64+s_si[0]]; }
      __syncthreads();
      const int isel=s_sel[0], hsel=s_sel[1], tsel=s_sel[2];
      const int wsi = (t<64)? t : isel;
      const int wsh = (t<64)? t : hsel;
      const int len = length[b];
      if (tid<64) {
        const int g = j*64 + tid;
        const size_t base=((size_t)t*32+b)*1536;
        float wi0=mem[OGIXM+base+g], wi1=mem[OGIXM+base+512+g], wi2=mem[OGIXM+base+1024+g];
        if (tsel>=0) {
          const size_t pb=((size_t)tsel*32+b)*1536;
          wi0+=mem[OPI+pb+g]; wi1+=mem[OPI+pb+512+g]; wi2+=mem[OPI+pb+1024+g];
        }
        const size_t hb=((size_t)b*64+hsel)*1536;
        const size_t g1b=(size_t)b*1536;
        const float wh0=mem[OG1+g1b+g]      + mem[OHG2+hb+g];
        const float wh1=mem[OG1+g1b+512+g]  + mem[OHG2+hb+512+g];
        const float wh2=mem[OG1+g1b+1024+g] + mem[OHG2+hb+1024+g];
        const float r=sigm(wi0+wh0), z=sigm(wi1+wh1);
        const float n=tanhf(wi2 + r*wh2);
        const float hold=mem[OHT + (g<<5) + b];
        const float h1=(1.f-z)*n + z*hold;
        const float hn = (t<len)? h1 : hold;
        mem[OHT + (g<<5) + b] = hn;
        mem[OYS + ((size_t)t*32+b)*512 + g] = hn;
        // hmem slot write: cache h@Whh2 of carry-in h at wsh (read of hsel above
        // and this write touch the same col-slice only within THIS WG).
        const size_t wb=((size_t)b*64+wsh)*1536;
        mem[OHG2+wb+g]      = mem[OG2+g1b+g];
        mem[OHG2+wb+512+g]  = mem[OG2+g1b+512+g];
        mem[OHG2+wb+1024+g] = mem[OG2+g1b+1024+g];
      } else if (j==1 && tid>=64 && tid<194) {
        const int c=tid-64;
        if (t<len) mem[OAUXT + (c<<5) + b] = s_rhs[c];
      } else if (j==0 && tid==200) {
        pend[b*8+0]=1; pend[b*8+1]=t; pend[b*8+2]=isel; pend[b*8+3]=hsel;
        pend[b*8+4]=wsi; pend[b*8+5]=wsh;
      }
    }
    gbar(2*t+2, alive);
  }
}

// ---------------------------------------------------------------------------
extern "C" void kernel_launch(void* const* d_in, const int* in_sizes, int n_in,
                              void* d_out, int out_size, void* d_ws, size_t ws_size,
                              hipStream_t stream)
{
  (void)in_sizes; (void)n_in; (void)out_size; (void)d_ws; (void)ws_size;
  const float* x      = (const float*)d_in[0];
  const int*   length = (const int*)  d_in[1];
  const float* fc1_w  = (const float*)d_in[2];
  const float* fc1_b  = (const float*)d_in[3];
  const float* w_ih   = (const float*)d_in[4];
  const float* w_hh   = (const float*)d_in[5];
  const float* b_ih   = (const float*)d_in[6];
  const float* b_hh   = (const float*)d_in[7];
  const float* aux_wih= (const float*)d_in[8];
  const float* aux_whh= (const float*)d_in[9];
  const float* aux_bih= (const float*)d_in[10];
  const float* aux_bhh= (const float*)d_in[11];
  const float* ifc_w1 = (const float*)d_in[12];
  const float* ifc_b1 = (const float*)d_in[13];
  const float* ifc_w2 = (const float*)d_in[14];
  const float* ifc_b2 = (const float*)d_in[15];
  const float* hfc_w1 = (const float*)d_in[16];
  const float* hfc_b1 = (const float*)d_in[17];
  const float* hfc_w2 = (const float*)d_in[18];
  const float* hfc_b2 = (const float*)d_in[19];
  const float* fc_w   = (const float*)d_in[20];
  const float* fc_b   = (const float*)d_in[21];
  const float* gum_i  = (const float*)d_in[22];
  const float* gum_h  = (const float*)d_in[23];
  float* out = (float*)d_out;

  float* gm = nullptr;
  hipGetSymbolAddress((void**)&gm, HIP_SYMBOL(g_mem));

  k_init<<<2048,256,0,stream>>>();
  // xp = x @ fc1_w + fc1_b
  k_gemm<<<dim3(64,8),256,0,stream>>>(x,500, fc1_w,512, fc1_b, gm+OXP,512, 512,500, 0);
  // gix_main = xp @ w_ih[:512] + b_ih
  k_gemm<<<dim3(64,24),256,0,stream>>>(gm+OXP,512, w_ih,1536, b_ih, gm+OGIXM,1536, 1536,512, 0);
  // P_i = xp @ w_ih[512:]
  k_gemm<<<dim3(64,24),256,0,stream>>>(gm+OXP,512, w_ih+(size_t)512*1536,1536, nullptr, gm+OPI,1536, 1536,512, 0);
  // gix_aux = xp @ aux_wih[:512] + aux_bih
  k_gemm<<<dim3(64,7),256,0,stream>>>(gm+OXP,512, aux_wih,390, aux_bih, gm+OGIXA,390, 390,512, 0);
  // ihid = relu(xp @ ifc_w1 + ifc_b1)
  k_gemm<<<dim3(64,1),256,0,stream>>>(gm+OXP,512, ifc_w1,32, ifc_b1, gm+OIHID,32, 32,512, 1);
  // imlp_x = sigmoid(ihid @ ifc_w2 + ifc_b2)
  k_gemm<<<dim3(64,1),256,0,stream>>>(gm+OIHID,32, ifc_w2,64, ifc_b2, gm+OIMLPX,64, 64,32, 2);
  // sequential scan (persistent kernel, 2 global barriers per step)
  k_scan<<<NWG,256,0,stream>>>(w_hh,b_hh,aux_wih,aux_whh,aux_bhh,
                               hfc_w1,hfc_b1,hfc_w2,hfc_b2,gum_i,gum_h,length);
  // out = ys @ fc_w + fc_b
  k_gemm<<<dim3(64,1),256,0,stream>>>(gm+OYS,512, fc_w,48, fc_b, out,48, 48,512, 0);
}

// Round 4
// 14435.936 us; speedup vs baseline: 4.7374x; 4.7374x over previous
//
#include <hip/hip_runtime.h>
#include <cmath>

// ---------------------------------------------------------------------------
// MaSST: memory-augmented GRU scan. T=128, B=32, F=500, H=512, M=64, HEAD=64.
// Round-2 (PASSED) structure: hoisted x-GEMMs, cached h@Whh2 / slot-MLP,
// persistent kernel, threadfence-based global barriers.
// Round-4 fix: spin with RELAXED load (round-2 spun with ACQUIRE -> a
// buffer_inv per spin iteration -> continuous L2 invalidation = 96 ms).
// One acquire __threadfence() after spin exit preserves correctness.
// ---------------------------------------------------------------------------

#define NWG 256
#define NEGV -9999999.0f

constexpr size_t OXP   = 0;                         // xp [4096,512]
constexpr size_t OGIXM = OXP   + 4096ull*512;       // xp@w_ih[:512]+b_ih [4096,1536]
constexpr size_t OPI   = OGIXM + 4096ull*1536;      // xp@w_ih[512:]      [4096,1536]
constexpr size_t OGIXA = OPI   + 4096ull*1536;      // xp@aux_wih[:512]+aux_bih [4096,390]
constexpr size_t OIHID = OGIXA + 4096ull*390;       // relu(xp@ifc_w1+b1) [4096,32]
constexpr size_t OIMLPX= OIHID + 4096ull*32;        // sigmoid(ihid@ifc_w2+b2) [4096,64]
constexpr size_t OHT   = OIMLPX+ 4096ull*64;        // h transposed [512][32]
constexpr size_t OAUXT = OHT   + 512ull*32;         // aux transposed [130][32]
constexpr size_t ORH   = OAUXT + 130ull*32;         // read_head [32][130]
constexpr size_t OG1   = ORH   + 130ull*32;         // h@Whh1+b_hh [32][1536]
constexpr size_t OG2   = OG1   + 32ull*1536;        // h@Whh2      [32][1536]
constexpr size_t OHG2  = OG2   + 32ull*1536;        // cache: hmem_slot@Whh2 [32][64][1536]
constexpr size_t OIC   = OHG2  + 32ull*64*1536;     // i mlp cache [32][64][64]
constexpr size_t OHC   = OIC   + 32ull*64*64;       // h mlp cache [32][64][64]
constexpr size_t OILU  = OHC   + 32ull*64*64;       // [32][64]
constexpr size_t OHLU  = OILU  + 2048;
constexpr size_t OISL  = OHLU  + 2048;              // int: slot -> time (or -1)
constexpr size_t OHID  = OISL  + 2048;              // hidden dbuf [2][32][32]
constexpr size_t OPEND = OHID  + 2048;              // int pend [32][8]
constexpr size_t OBAR  = OPEND + 256;               // int barrier counter
constexpr size_t OYS   = OBAR  + 64;                // ys [4096,512]
constexpr size_t OTOT  = OYS   + 4096ull*512;

__device__ float g_mem[OTOT];

__device__ __forceinline__ float sigm(float x){ return 1.0f/(1.0f+expf(-x)); }

// ---------------------------------------------------------------------------
__global__ void k_init() {
  size_t i = (size_t)blockIdx.x*blockDim.x + threadIdx.x;
  size_t st = (size_t)gridDim.x*blockDim.x;
  for (size_t k=i; k<32ull*64*1536; k+=st) g_mem[OHG2+k]=0.f;
  for (size_t k=i; k<32ull*64*64; k+=st){ g_mem[OIC+k]=0.5f; g_mem[OHC+k]=0.5f; } // MLP(0)=sigmoid(0)=0.5
  for (size_t k=i; k<2048; k+=st){ g_mem[OILU+k]=NEGV; g_mem[OHLU+k]=NEGV; ((int*)(g_mem+OISL))[k]=-1; }
  for (size_t k=i; k<512ull*32; k+=st) g_mem[OHT+k]=0.f;
  for (size_t k=i; k<130ull*32; k+=st) g_mem[OAUXT+k]=0.f;
  for (size_t k=i; k<320; k+=st) ((int*)(g_mem+OPEND))[k]=0;   // pend(256) + bar(64)
}

// ---------------------------------------------------------------------------
// Generic fp32 tiled GEMM: C[M=4096, N] = act(A[4096,K] @ B[K,N] + bias)
// act: 0 none, 1 relu, 2 sigmoid.
__global__ __launch_bounds__(256) void k_gemm(
    const float* __restrict__ A, int lda,
    const float* __restrict__ B, int ldb,
    const float* __restrict__ bias,
    float* __restrict__ C, int ldc,
    int N, int K, int act)
{
  __shared__ float As[16][64];
  __shared__ float Bs[16][68];
  const int tid = threadIdx.x;
  const int row0 = blockIdx.x*64;
  const int col0 = blockIdx.y*64;
  const int tm = tid>>4, tn = tid&15;
  const int am = tid>>2, akq = tid&3;
  const int bk = tid>>4, bnq = tid&15;
  float acc[4][4] = {};
  for (int k0=0; k0<K; k0+=16) {
    { // stage A (64 rows x 16 k), store transposed As[k][m]
      int ak = k0 + akq*4;
      const float* Ap = A + (size_t)(row0+am)*lda + ak;
      float4 av;
      if (ak+3 < K) av = *(const float4*)Ap;
      else {
        av.x=(ak+0<K)?Ap[0]:0.f; av.y=(ak+1<K)?Ap[1]:0.f;
        av.z=(ak+2<K)?Ap[2]:0.f; av.w=(ak+3<K)?Ap[3]:0.f;
      }
      As[akq*4+0][am]=av.x; As[akq*4+1][am]=av.y; As[akq*4+2][am]=av.z; As[akq*4+3][am]=av.w;
    }
    { // stage B (16 k x 64 n)
      int kk = k0 + bk;
      int cb = col0 + bnq*4;
      float4 bv = {0.f,0.f,0.f,0.f};
      if (kk < K) {
        const float* Bp = B + (size_t)kk*ldb + cb;
        if (cb+3 < N && ((((size_t)kk*ldb + (size_t)cb)&3)==0)) bv = *(const float4*)Bp;
        else {
          bv.x=(cb+0<N)?Bp[0]:0.f; bv.y=(cb+1<N)?Bp[1]:0.f;
          bv.z=(cb+2<N)?Bp[2]:0.f; bv.w=(cb+3<N)?Bp[3]:0.f;
        }
      }
      Bs[bk][bnq*4+0]=bv.x; Bs[bk][bnq*4+1]=bv.y; Bs[bk][bnq*4+2]=bv.z; Bs[bk][bnq*4+3]=bv.w;
    }
    __syncthreads();
    #pragma unroll
    for (int k=0;k<16;++k) {
      float a0=As[k][tm*4+0], a1=As[k][tm*4+1], a2=As[k][tm*4+2], a3=As[k][tm*4+3];
      float b0=Bs[k][tn*4+0], b1=Bs[k][tn*4+1], b2=Bs[k][tn*4+2], b3=Bs[k][tn*4+3];
      acc[0][0]=fmaf(a0,b0,acc[0][0]); acc[0][1]=fmaf(a0,b1,acc[0][1]);
      acc[0][2]=fmaf(a0,b2,acc[0][2]); acc[0][3]=fmaf(a0,b3,acc[0][3]);
      acc[1][0]=fmaf(a1,b0,acc[1][0]); acc[1][1]=fmaf(a1,b1,acc[1][1]);
      acc[1][2]=fmaf(a1,b2,acc[1][2]); acc[1][3]=fmaf(a1,b3,acc[1][3]);
      acc[2][0]=fmaf(a2,b0,acc[2][0]); acc[2][1]=fmaf(a2,b1,acc[2][1]);
      acc[2][2]=fmaf(a2,b2,acc[2][2]); acc[2][3]=fmaf(a2,b3,acc[2][3]);
      acc[3][0]=fmaf(a3,b0,acc[3][0]); acc[3][1]=fmaf(a3,b1,acc[3][1]);
      acc[3][2]=fmaf(a3,b2,acc[3][2]); acc[3][3]=fmaf(a3,b3,acc[3][3]);
    }
    __syncthreads();
  }
  for (int i=0;i<4;++i)
    for (int j2=0;j2<4;++j2) {
      int r = row0+tm*4+i, c = col0+tn*4+j2;
      if (c<N) {
        float v = acc[i][j2] + (bias? bias[c]:0.f);
        if (act==1) v = fmaxf(v,0.f);
        else if (act==2) v = 1.f/(1.f+expf(-v));
        C[(size_t)r*ldc + c] = v;
      }
    }
}

// ---------------------------------------------------------------------------
// Global barrier: monotonic counter, barrier #n passes when cnt >= n*NWG.
// Release: __threadfence (wbl2) BEFORE add. Spin: RELAXED loads (no cache
// maintenance per iteration!). Acquire: ONE __threadfence after spin exit.
__device__ __forceinline__ void gbar(int n, int& alive) {
  __syncthreads();   // compiler emits s_waitcnt vmcnt(0) lgkmcnt(0) before s_barrier
  if (threadIdx.x==0 && alive) {
    int* bar = (int*)(g_mem+OBAR);
    __threadfence();                 // release: flush my writes to coherence point
    atomicAdd(bar, 1);
    const int target = n*NWG;
    int guard = 0;
    while (__hip_atomic_load(bar, __ATOMIC_RELAXED, __HIP_MEMORY_SCOPE_AGENT) < target) {
      __builtin_amdgcn_s_sleep(4);
      if (++guard > (1<<20)) { alive=0; break; }   // bail instead of hanging
    }
    __threadfence();                 // acquire: one invalidate after spin
  }
  __syncthreads();
}

// ---------------------------------------------------------------------------
__global__ __launch_bounds__(256,1) void k_scan(
    const float* __restrict__ w_hh, const float* __restrict__ b_hh,
    const float* __restrict__ aux_wih, const float* __restrict__ aux_whh,
    const float* __restrict__ aux_bhh,
    const float* __restrict__ hfc_w1, const float* __restrict__ hfc_b1,
    const float* __restrict__ hfc_w2, const float* __restrict__ hfc_b2,
    const float* __restrict__ gum_i, const float* __restrict__ gum_h,
    const int* __restrict__ length)
{
  const int wg  = blockIdx.x;
  const int tid = threadIdx.x;
  float* const mem = g_mem;
  int*  const islot = (int*)(mem+OISL);
  int*  const pend  = (int*)(mem+OPEND);

  __shared__ float s_red[2][4][64];
  __shared__ float s_sp[5][4][2][32];
  __shared__ float s_ph[32][9];
  __shared__ float s_rhs[132];
  __shared__ float s_sv[128];
  __shared__ int   s_si[128];
  __shared__ int   s_sel[4];
  __shared__ int   s_pd[8];

  int alive = 1;

  #pragma unroll 1
  for (int t=0; t<128; ++t) {
    // ================= H-phase: everything depending only on carry h/aux ====
    if (wg < 192) {
      // G1 = h@Whh1 + b_hh ; G2 = h@Whh2.  3072 virtual cols over 48 groups.
      const int cg = wg>>2, bg = wg&3;
      const int wave = tid>>6, lane = tid&63;
      const int vcol = cg*64 + lane;
      const int isG2 = vcol>=1536;
      const int col  = isG2? vcol-1536 : vcol;
      const float* Wp = w_hh + (size_t)(isG2?512:0)*1536 + col;
      const int bh = wave>>1, kh = wave&1;
      const int b0 = bg*8 + bh*4;
      const float* hTp = mem+OHT;
      float a0=0.f,a1=0.f,a2=0.f,a3=0.f;
      const int kbeg = kh*256;
      #pragma unroll 8
      for (int k=kbeg; k<kbeg+256; ++k) {
        const float w = Wp[(size_t)k*1536];
        const float4 hv = *(const float4*)(hTp + (k<<5) + b0);
        a0 = fmaf(w,hv.x,a0); a1 = fmaf(w,hv.y,a1);
        a2 = fmaf(w,hv.z,a2); a3 = fmaf(w,hv.w,a3);
      }
      if (kh) { s_red[bh][0][lane]=a0; s_red[bh][1][lane]=a1; s_red[bh][2][lane]=a2; s_red[bh][3][lane]=a3; }
      __syncthreads();
      if (!kh) {
        a0+=s_red[bh][0][lane]; a1+=s_red[bh][1][lane]; a2+=s_red[bh][2][lane]; a3+=s_red[bh][3][lane];
        const float bias = isG2 ? 0.f : b_hh[vcol];
        float* Gp = mem + (isG2? OG2 : OG1);
        Gp[(size_t)(b0+0)*1536+col]=a0+bias;
        Gp[(size_t)(b0+1)*1536+col]=a1+bias;
        Gp[(size_t)(b0+2)*1536+col]=a2+bias;
        Gp[(size_t)(b0+3)*1536+col]=a3+bias;
      }
    } else if (wg < 224) {
      // aux GRU read_head. rh-cols [c0,c1) for this WG.
      const int a = wg-192;
      const int c0 = (a*130)>>5, c1 = ((a+1)*130)>>5;
      const int nc = c1-c0;
      const int nt = nc*256;
      const float* hTp = mem+OHT;
      const float* axp = mem+OAUXT;
      for (int task=tid; task<nt; task+=256) {
        const int b=task&31, kh=(task>>5)&1, gate=(task>>6)&3, rcl=task>>8;
        const int c = c0+rcl;
        float acc=0.f;
        if (gate != 3) {                       // h-part dot (r,z merged; n separate)
          const int gc = (gate==2? 260 : gate*130) + c;
          const float* W = aux_wih + (size_t)512*390 + gc;
          const int kb = kh*256;
          #pragma unroll 8
          for (int k=kb;k<kb+256;++k) acc = fmaf(hTp[(k<<5)+b], W[(size_t)k*390], acc);
        }
        if (gate != 2) {                       // aux-part dot
          const int gc = (gate==3? 260 : gate*130) + c;
          const float* W2 = aux_whh + gc;
          const int kb = kh*65;
          for (int k=kb;k<kb+65;++k) acc = fmaf(axp[(k<<5)+b], W2[(size_t)k*390], acc);
        }
        s_sp[rcl][gate][kh][b] = acc;
      }
      __syncthreads();
      for (int task=tid; task<nc*32; task+=256) {
        const int b=task&31, rcl=task>>5;
        const int c=c0+rcl;
        const size_t base=((size_t)t*32+b)*390;
        const float r = sigm(mem[OGIXA+base+c]     + aux_bhh[c]     + s_sp[rcl][0][0][b]+s_sp[rcl][0][1][b]);
        const float z = sigm(mem[OGIXA+base+130+c] + aux_bhh[130+c] + s_sp[rcl][1][0][b]+s_sp[rcl][1][1][b]);
        const float gin = mem[OGIXA+base+260+c] + s_sp[rcl][2][0][b]+s_sp[rcl][2][1][b];
        const float ghn = aux_bhh[260+c]        + s_sp[rcl][3][0][b]+s_sp[rcl][3][1][b];
        const float n = tanhf(gin + r*ghn);
        mem[ORH + (size_t)b*130 + c] = (1.f-z)*n + z*axp[(c<<5)+b];
      }
    } else {
      // mlph WG: deferred cache updates from step t-1, then hidden = relu(h@hfc_w1)
      const int b = wg-224;
      if (tid<8) s_pd[tid] = pend[b*8+tid];
      __syncthreads();
      if (s_pd[0]) {
        const int tp=s_pd[1], isel=s_pd[2], hsel=s_pd[3], wsi=s_pd[4], wsh=s_pd[5];
        if (tid<64) {
          mem[OIC + ((size_t)b*64+wsi)*64 + tid] = mem[OIMLPX + ((size_t)tp*32+b)*64 + tid];
        } else if (tid<128) {
          const int j2=tid-64;
          float s = hfc_b2[j2];
          const float* hid = mem + OHID + (size_t)(tp&1)*1024 + b*32;
          #pragma unroll 8
          for (int q=0;q<32;++q) s = fmaf(hid[q], hfc_w2[(size_t)q*64+j2], s);
          mem[OHC + ((size_t)b*64+wsh)*64 + j2] = sigm(s);
        } else if (tid<192) {
          const int m=tid-128;
          const float v = mem[OILU + b*64 + m];
          mem[OILU + b*64 + m] = (m==isel)? 0.f : (v-1.f);
        } else {
          const int m=tid-192;
          const float v = mem[OHLU + b*64 + m];
          mem[OHLU + b*64 + m] = (m==hsel)? 0.f : (v-1.f);
        }
        if (tid==0) islot[b*64+wsi] = tp;
      }
      __syncthreads();
      { // hidden_new
        const int j = tid&31, kq = tid>>5;
        const float* hTp = mem+OHT;
        float acc=0.f;
        const int kb = kq*64;
        #pragma unroll 4
        for (int k=kb;k<kb+64;++k) acc = fmaf(hTp[(k<<5)+b], hfc_w1[(size_t)k*32+j], acc);
        s_ph[j][kq]=acc;
      }
      __syncthreads();
      if (tid<32) {
        float s = hfc_b1[tid];
        #pragma unroll
        for (int q=0;q<8;++q) s += s_ph[tid][q];
        mem[OHID + (size_t)(t&1)*1024 + b*32 + tid] = fmaxf(s,0.f);
      }
    }
    gbar(2*t+1, alive);

    // ================= S-phase: scores, argmax, gather, gate combine ========
    {
      const int b = wg>>3, j = wg&7;
      if (tid<130) s_rhs[tid] = mem[ORH + (size_t)b*130 + tid];
      __syncthreads();
      if (tid<128) {
        const int head=tid>>6, m=tid&63;
        const float* cache = mem + (head? OHC:OIC) + ((size_t)b*64+m)*64;
        const float* rh = s_rhs + head*65;
        float acc=0.f;
        #pragma unroll 16
        for (int k=0;k<64;++k) acc = fmaf(rh[k], cache[k], acc);
        const float lu = mem[(head? OHLU:OILU) + b*64 + m];
        acc += rh[64]*sigm(lu);
        acc += (head? gum_h:gum_i)[((size_t)t*32+b)*64+m];
        s_sv[tid]=acc; s_si[tid]=m;
      }
      __syncthreads();
      for (int off=32; off>0; off>>=1) {
        if (tid<128 && (tid&63)<off) {
          const float v2=s_sv[tid+off]; const int i2=s_si[tid+off];
          if (v2>s_sv[tid] || (v2==s_sv[tid] && i2<s_si[tid])) { s_sv[tid]=v2; s_si[tid]=i2; }
        }
        __syncthreads();
      }
      if (tid==0) { s_sel[0]=s_si[0]; s_sel[1]=s_si[64]; s_sel[2]=islot[b*64+s_si[0]]; }
      __syncthreads();
      const int isel=s_sel[0], hsel=s_sel[1], tsel=s_sel[2];
      const int wsi = (t<64)? t : isel;
      const int wsh = (t<64)? t : hsel;
      const int len = length[b];
      if (tid<64) {
        const int g = j*64 + tid;
        const size_t base=((size_t)t*32+b)*1536;
        float wi0=mem[OGIXM+base+g], wi1=mem[OGIXM+base+512+g], wi2=mem[OGIXM+base+1024+g];
        if (tsel>=0) {
          const size_t pb=((size_t)tsel*32+b)*1536;
          wi0+=mem[OPI+pb+g]; wi1+=mem[OPI+pb+512+g]; wi2+=mem[OPI+pb+1024+g];
        }
        const size_t hb=((size_t)b*64+hsel)*1536;
        const size_t g1b=(size_t)b*1536;
        const float wh0=mem[OG1+g1b+g]      + mem[OHG2+hb+g];
        const float wh1=mem[OG1+g1b+512+g]  + mem[OHG2+hb+512+g];
        const float wh2=mem[OG1+g1b+1024+g] + mem[OHG2+hb+1024+g];
        const float r=sigm(wi0+wh0), z=sigm(wi1+wh1);
        const float n=tanhf(wi2 + r*wh2);
        const float hold=mem[OHT + (g<<5) + b];
        const float h1=(1.f-z)*n + z*hold;
        const float hn = (t<len)? h1 : hold;
        mem[OHT + (g<<5) + b] = hn;
        mem[OYS + ((size_t)t*32+b)*512 + g] = hn;
        // hmem slot write: cache h@Whh2 of carry-in h at wsh (read of hsel above
        // and this write touch the same col-slice only within THIS WG).
        const size_t wb=((size_t)b*64+wsh)*1536;
        mem[OHG2+wb+g]      = mem[OG2+g1b+g];
        mem[OHG2+wb+512+g]  = mem[OG2+g1b+512+g];
        mem[OHG2+wb+1024+g] = mem[OG2+g1b+1024+g];
      } else if (j==1 && tid>=64 && tid<194) {
        const int c=tid-64;
        if (t<len) mem[OAUXT + (c<<5) + b] = s_rhs[c];
      } else if (j==0 && tid==200) {
        pend[b*8+0]=1; pend[b*8+1]=t; pend[b*8+2]=isel; pend[b*8+3]=hsel;
        pend[b*8+4]=wsi; pend[b*8+5]=wsh;
      }
    }
    gbar(2*t+2, alive);
  }
}

// ---------------------------------------------------------------------------
extern "C" void kernel_launch(void* const* d_in, const int* in_sizes, int n_in,
                              void* d_out, int out_size, void* d_ws, size_t ws_size,
                              hipStream_t stream)
{
  (void)in_sizes; (void)n_in; (void)out_size; (void)d_ws; (void)ws_size;
  const float* x      = (const float*)d_in[0];
  const int*   length = (const int*)  d_in[1];
  const float* fc1_w  = (const float*)d_in[2];
  const float* fc1_b  = (const float*)d_in[3];
  const float* w_ih   = (const float*)d_in[4];
  const float* w_hh   = (const float*)d_in[5];
  const float* b_ih   = (const float*)d_in[6];
  const float* b_hh   = (const float*)d_in[7];
  const float* aux_wih= (const float*)d_in[8];
  const float* aux_whh= (const float*)d_in[9];
  const float* aux_bih= (const float*)d_in[10];
  const float* aux_bhh= (const float*)d_in[11];
  const float* ifc_w1 = (const float*)d_in[12];
  const float* ifc_b1 = (const float*)d_in[13];
  const float* ifc_w2 = (const float*)d_in[14];
  const float* ifc_b2 = (const float*)d_in[15];
  const float* hfc_w1 = (const float*)d_in[16];
  const float* hfc_b1 = (const float*)d_in[17];
  const float* hfc_w2 = (const float*)d_in[18];
  const float* hfc_b2 = (const float*)d_in[19];
  const float* fc_w   = (const float*)d_in[20];
  const float* fc_b   = (const float*)d_in[21];
  const float* gum_i  = (const float*)d_in[22];
  const float* gum_h  = (const float*)d_in[23];
  float* out = (float*)d_out;

  float* gm = nullptr;
  hipGetSymbolAddress((void**)&gm, HIP_SYMBOL(g_mem));

  k_init<<<2048,256,0,stream>>>();
  // xp = x @ fc1_w + fc1_b
  k_gemm<<<dim3(64,8),256,0,stream>>>(x,500, fc1_w,512, fc1_b, gm+OXP,512, 512,500, 0);
  // gix_main = xp @ w_ih[:512] + b_ih
  k_gemm<<<dim3(64,24),256,0,stream>>>(gm+OXP,512, w_ih,1536, b_ih, gm+OGIXM,1536, 1536,512, 0);
  // P_i = xp @ w_ih[512:]
  k_gemm<<<dim3(64,24),256,0,stream>>>(gm+OXP,512, w_ih+(size_t)512*1536,1536, nullptr, gm+OPI,1536, 1536,512, 0);
  // gix_aux = xp @ aux_wih[:512] + aux_bih
  k_gemm<<<dim3(64,7),256,0,stream>>>(gm+OXP,512, aux_wih,390, aux_bih, gm+OGIXA,390, 390,512, 0);
  // ihid = relu(xp @ ifc_w1 + ifc_b1)
  k_gemm<<<dim3(64,1),256,0,stream>>>(gm+OXP,512, ifc_w1,32, ifc_b1, gm+OIHID,32, 32,512, 1);
  // imlp_x = sigmoid(ihid @ ifc_w2 + ifc_b2)
  k_gemm<<<dim3(64,1),256,0,stream>>>(gm+OIHID,32, ifc_w2,64, ifc_b2, gm+OIMLPX,64, 64,32, 2);
  // sequential scan (persistent kernel, 2 global barriers per step)
  k_scan<<<NWG,256,0,stream>>>(w_hh,b_hh,aux_wih,aux_whh,aux_bhh,
                               hfc_w1,hfc_b1,hfc_w2,hfc_b2,gum_i,gum_h,length);
  // out = ys @ fc_w + fc_b
  k_gemm<<<dim3(64,1),256,0,stream>>>(gm+OYS,512, fc_w,48, fc_b, out,48, 48,512, 0);
}